// Round 17
// baseline (1769.986 us; speedup 1.0000x reference)
//
#include <hip/hip_runtime.h>
#include <hip/hip_bf16.h>

using bf16 = __hip_bfloat16;

typedef __attribute__((ext_vector_type(4))) float f32x4;
typedef __attribute__((ext_vector_type(8))) short short8;

typedef const void __attribute__((address_space(1)))* gas1_t;
typedef void __attribute__((address_space(3)))* las3_t;
#define GLDS(gp, lp) __builtin_amdgcn_global_load_lds((gas1_t)(gp), (las3_t)(lp), 16, 0, 0)

__device__ inline short f2bfbits(float f) {
  union { bf16 h; short s; } u;
  u.h = __float2bfloat16(f);
  return u.s;
}
__device__ inline float bf2f(short u) {
  unsigned x = ((unsigned)(unsigned short)u) << 16;
  float f; __builtin_memcpy(&f, &x, 4); return f;
}

__device__ inline void store_out(float* C, size_t idx, float v) { C[idx] = v; }
__device__ inline void store_out(bf16* C, size_t idx, float v) { C[idx] = __float2bfloat16(v); }

// ---------------------------------------------------------------------------
// 256x256 tile GEMM, BK=32, 512 thr = 8 waves (2M x 4N) — 2-BUFFER variant:
// 64 KB LDS -> 2 blocks/CU (vs 3-ring's 96 KB -> 1 block/CU). Cross-block
// TLP covers the per-tile drain (m114 wave-overlap — the mechanism behind the
// 128^2 kernel's 640 TF). r3-philosophy loop: stage(kt+1) early into buf^1,
// ONE plain __syncthreads per K-tile, compiler-scheduled waits, no inline-asm
// scheduling (m141). Chunk-XOR swizzle kept (r15 vs r16: 384 vs 395 us).
// MODE 0: plain, identity raster.
// MODE 1: causal S -> tri grid, C to 256-packed tri bf16.
// MODE 2: PV -> A is 256-packed P, K limited to (by+1)*256.
// ---------------------------------------------------------------------------
template<typename TOUT, int MODE>
__global__ __launch_bounds__(512, 4) void gemm256(
    const short* __restrict__ A, int lda, size_t sAz,
    const short* __restrict__ B, int ldb, size_t sBz,
    TOUT* __restrict__ C, int ldc, size_t sCz,
    int K, float scale)
{
  int bx, by;
  if constexpr (MODE == 1) {
    const int i = blockIdx.x;
    by = (int)((__builtin_sqrtf(8.f * (float)i + 1.f) - 1.f) * 0.5f);
    if (((by * (by + 1)) >> 1) > i) by--;
    else if ((((by + 1) * (by + 2)) >> 1) <= i) by++;
    bx = i - ((by * (by + 1)) >> 1);
  } else {
    bx = blockIdx.x; by = blockIdx.y;
  }
  const int z = blockIdx.z;
  const int tri_by = (by * (by + 1)) >> 1;

  A += (size_t)z * sAz;
  B += (size_t)z * sBz;
  C += (size_t)z * sCz;

  int Klen = K;
  if (MODE == 2) Klen = min(K, (by + 1) * 256);
  const int NT = Klen >> 5;

  __shared__ short As[2][256 * 32];   // 2 x 16 KB
  __shared__ short Bs[2][256 * 32];   // 2 x 16 KB  (total 64 KB -> 2 blocks/CU)

  const int t = threadIdx.x;
  const int lane = t & 63;
  const int wave = t >> 6;
  const int wm = wave >> 2;
  const int wn = wave & 3;
  const int fr = lane & 15, kh = lane >> 4;
  const int koff = ((kh ^ ((fr >> 1) & 3)) << 3);   // swizzled 8-short chunk

  int srow[2], scol[2];
  #pragma unroll
  for (int j = 0; j < 2; j++) {
    int e = j * 512 + t;
    srow[j] = e >> 2;
    scol[j] = (((e & 3) ^ ((e >> 3) & 3)) << 3);    // pre-swizzled source
  }

  f32x4 acc[8][4];
  #pragma unroll
  for (int i = 0; i < 8; i++)
    #pragma unroll
    for (int j = 0; j < 4; j++) acc[i][j] = (f32x4){0.f, 0.f, 0.f, 0.f};

  auto STAGE = [&](int kt) {
    const int buf = kt & 1, k0 = kt * 32;
    #pragma unroll
    for (int j = 0; j < 2; j++) {
      const short* pa;
      if constexpr (MODE == 2)
        pa = A + (size_t)(tri_by + (k0 >> 8)) * 65536 + (size_t)srow[j] * 256 + (k0 & 255) + scol[j];
      else
        pa = A + (size_t)(by * 256 + srow[j]) * lda + k0 + scol[j];
      GLDS(pa, (char*)&As[buf][0] + j * 8192 + wave * 1024);
      const short* pb = B + (size_t)(bx * 256 + srow[j]) * ldb + k0 + scol[j];
      GLDS(pb, (char*)&Bs[buf][0] + j * 8192 + wave * 1024);
    }
  };

  STAGE(0);
  __syncthreads();

  const int arow = wm * 128 + fr;
  const int brow = wn * 64 + fr;

  for (int kt = 0; kt < NT; kt++) {
    const short* as = &As[kt & 1][0];
    const short* bs = &Bs[kt & 1][0];

    if (kt + 1 < NT) STAGE(kt + 1);   // into buf^1; lands at this tile's barrier

    short8 af[8], bfr[4];
    #pragma unroll
    for (int n = 0; n < 4; n++) bfr[n] = *(const short8*)&bs[(brow + n * 16) * 32 + koff];
    #pragma unroll
    for (int m = 0; m < 8; m++) af[m] = *(const short8*)&as[(arow + m * 16) * 32 + koff];

    #pragma unroll
    for (int m = 0; m < 8; m++)
      #pragma unroll
      for (int n = 0; n < 4; n++)
        acc[m][n] = __builtin_amdgcn_mfma_f32_16x16x32_bf16(af[m], bfr[n], acc[m][n], 0, 0, 0);

    __syncthreads();   // drains vmcnt+lgkm: stage landed, all reads of buf done
  }

  #pragma unroll
  for (int m = 0; m < 8; m++)
    #pragma unroll
    for (int n = 0; n < 4; n++) {
      int col_l = wn * 64 + n * 16 + fr;
      #pragma unroll
      for (int r = 0; r < 4; r++) {
        int row_l = wm * 128 + m * 16 + kh * 4 + r;
        if constexpr (MODE == 1)
          store_out(C, (size_t)(tri_by + bx) * 65536 + (size_t)row_l * 256 + col_l,
                    acc[m][n][r] * scale);
        else
          store_out(C, (size_t)(by * 256 + row_l) * ldc + bx * 256 + col_l,
                    acc[m][n][r] * scale);
      }
    }
}

// ---------------------------------------------------------------------------
// Small 128x128 GEMM (round-3 proven loop) — only for W2T = Wk^T.Wq (8x8).
// ---------------------------------------------------------------------------
__global__ __launch_bounds__(256) void gemm128(
    const short* __restrict__ A, int lda,
    const short* __restrict__ B, int ldb,
    bf16* __restrict__ C, int ldc, int K, float scale)
{
  const int bx = blockIdx.x, by = blockIdx.y;
  __shared__ short a_lds[128 * 32];
  __shared__ short b_lds[128 * 32];

  const int t = threadIdx.x;
  const int lane = t & 63;
  const int wave = t >> 6;
  const int wm = wave >> 1, wn = wave & 1;
  const int fr = lane & 15, kh = lane >> 4;

  f32x4 acc[4][4];
  #pragma unroll
  for (int i = 0; i < 4; i++)
    #pragma unroll
    for (int j = 0; j < 4; j++) acc[i][j] = (f32x4){0.f, 0.f, 0.f, 0.f};

  for (int k0 = 0; k0 < K; k0 += 32) {
    #pragma unroll
    for (int i = 0; i < 2; i++) {
      int e = i * 256 + t;
      int r_ = e >> 2, c_ = (e & 3) * 8;
      GLDS(A + (size_t)(by * 128 + r_) * lda + k0 + c_, (char*)a_lds + i * 4096 + wave * 1024);
      GLDS(B + (size_t)(bx * 128 + r_) * ldb + k0 + c_, (char*)b_lds + i * 4096 + wave * 1024);
    }
    __syncthreads();

    short8 af[4], bfr[4];
    #pragma unroll
    for (int m = 0; m < 4; m++)
      af[m] = *(const short8*)&a_lds[(wm * 64 + m * 16 + fr) * 32 + kh * 8];
    #pragma unroll
    for (int n = 0; n < 4; n++)
      bfr[n] = *(const short8*)&b_lds[(wn * 64 + n * 16 + fr) * 32 + kh * 8];
    #pragma unroll
    for (int m = 0; m < 4; m++)
      #pragma unroll
      for (int n = 0; n < 4; n++)
        acc[m][n] = __builtin_amdgcn_mfma_f32_16x16x32_bf16(af[m], bfr[n], acc[m][n], 0, 0, 0);
    __syncthreads();
  }

  #pragma unroll
  for (int m = 0; m < 4; m++)
    #pragma unroll
    for (int n = 0; n < 4; n++) {
      int col = bx * 128 + wn * 64 + n * 16 + fr;
      #pragma unroll
      for (int r = 0; r < 4; r++) {
        int row = by * 128 + wm * 64 + m * 16 + kh * 4 + r;
        C[(size_t)row * ldc + col] = __float2bfloat16(acc[m][n][r] * scale);
      }
    }
}

// fp32 -> bf16 elementwise convert with scale
__global__ __launch_bounds__(256) void cvt_bf16(
    const float* __restrict__ in, bf16* __restrict__ out, int n, float scale)
{
  for (int i = (blockIdx.x * 256 + threadIdx.x) * 8; i < n; i += gridDim.x * 2048) {
    f32x4 v0 = *(const f32x4*)&in[i];
    f32x4 v1 = *(const f32x4*)&in[i + 4];
    short8 o = { f2bfbits(v0[0] * scale), f2bfbits(v0[1] * scale),
                 f2bfbits(v0[2] * scale), f2bfbits(v0[3] * scale),
                 f2bfbits(v1[0] * scale), f2bfbits(v1[1] * scale),
                 f2bfbits(v1[2] * scale), f2bfbits(v1[3] * scale) };
    *(short8*)&out[i] = o;
  }
}

// fp32 (N x N) -> bf16 transposed (N x N): out[c][r] = in[r][c]. 64x64 tiles.
__global__ __launch_bounds__(256) void cvt_t_bf16(
    const float* __restrict__ in, bf16* __restrict__ out, int N)
{
  __shared__ float tile[64][65];
  const int bx = blockIdx.x, by = blockIdx.y;
  const int t = threadIdx.x;
  #pragma unroll
  for (int i = 0; i < 16; i++) {
    int e = i * 256 + t;
    int r = e >> 6, c = e & 63;
    tile[r][c] = in[(size_t)(by * 64 + r) * N + bx * 64 + c];
  }
  __syncthreads();
  #pragma unroll
  for (int i = 0; i < 16; i++) {
    int e = i * 256 + t;
    int r = e >> 6, c = e & 63;
    out[(size_t)(bx * 64 + r) * N + by * 64 + c] = __float2bfloat16(tile[c][r]);
  }
}

// In-place softmax on 256-packed block-triangular bf16 scores.
__global__ __launch_bounds__(256) void softmax_causal_packed(short* SP, int T)
{
  __shared__ float rowv[4096];
  __shared__ float red[4];
  const int r = blockIdx.x;
  const int z = blockIdx.y;
  const int rb = r >> 8, rl = r & 255;
  const size_t tri = (size_t)((rb * (rb + 1)) >> 1);
  short* base = SP + (size_t)z * 136 * 65536;
  const int L = r + 1;
  const int kend = (rb + 1) * 256;
  const int t = threadIdx.x;

  float lmax = -3.0e38f;
  for (int i = t * 8; i < kend; i += 2048) {
    short8 s = *(const short8*)(base + (tri + (i >> 8)) * 65536 + (size_t)rl * 256 + (i & 255));
    #pragma unroll
    for (int j = 0; j < 8; j++) {
      float v = bf2f(s[j]);
      rowv[i + j] = v;
      if (i + j < L) lmax = fmaxf(lmax, v);
    }
  }
  #pragma unroll
  for (int o = 32; o > 0; o >>= 1) lmax = fmaxf(lmax, __shfl_down(lmax, o));
  if ((t & 63) == 0) red[t >> 6] = lmax;
  __syncthreads();
  const float m = fmaxf(fmaxf(red[0], red[1]), fmaxf(red[2], red[3]));
  __syncthreads();

  float lsum = 0.f;
  for (int i = t; i < kend; i += 256) {
    float e = (i < L) ? __expf(rowv[i] - m) : 0.f;
    rowv[i] = e;
    lsum += e;
  }
  #pragma unroll
  for (int o = 32; o > 0; o >>= 1) lsum += __shfl_down(lsum, o);
  if ((t & 63) == 0) red[t >> 6] = lsum;
  __syncthreads();
  const float inv = 1.f / (red[0] + red[1] + red[2] + red[3]);

  for (int i = t * 8; i < kend; i += 2048) {
    short8 o;
    #pragma unroll
    for (int j = 0; j < 8; j++) o[j] = f2bfbits(rowv[i + j] * inv);
    *(short8*)(base + (tri + (i >> 8)) * 65536 + (size_t)rl * 256 + (i & 255)) = o;
  }
}

extern "C" void kernel_launch(void* const* d_in, const int* in_sizes, int n_in,
                              void* d_out, int out_size, void* d_ws, size_t ws_size,
                              hipStream_t stream) {
  (void)in_sizes; (void)n_in; (void)out_size; (void)ws_size;
  const float* X  = (const float*)d_in[0];   // (B,T,E)
  const float* Wq = (const float*)d_in[1];   // (A,E)
  const float* Wk = (const float*)d_in[2];
  const float* Wv = (const float*)d_in[3];
  float* Out = (float*)d_out;                // (B,T,A) fp32

  const int Bn = 4, T = 4096, E = 1024, Ad = 1024;
  const int M = Bn * T;  // 16384

  // Algebra: S = X.(Wq^T Wk / 32).X^T  — K-projection eliminated
  char* ws = (char*)d_ws;
  short* Q2  = (short*)ws;                    // [0,32Mi)   M x 1024
  short* Vt  = (short*)(ws + 33554432);       // [32,64Mi)  Ad x M
  short* Xb  = (short*)(ws + 67108864);       // [64,96Mi)  M x E
  short* WqT = (short*)(ws + 100663296);      // E x A
  short* WkT = (short*)(ws + 102760448);
  short* Wvb = (short*)(ws + 104857600);
  short* W2T = (short*)(ws + 106954752);
  short* SP  = (short*)(ws + 109051904);      // 4 x 136 x 256x256 bf16

  dim3 blk(256), blk5(512);
  const size_t SPz = (size_t)136 * 65536;

  // conversions
  cvt_bf16<<<dim3(8192), blk, 0, stream>>>(X, (bf16*)Xb, M * E, 1.0f);
  cvt_t_bf16<<<dim3(16, 16), blk, 0, stream>>>(Wq, (bf16*)WqT, E);
  cvt_t_bf16<<<dim3(16, 16), blk, 0, stream>>>(Wk, (bf16*)WkT, E);
  cvt_bf16<<<dim3(512), blk, 0, stream>>>(Wv, (bf16*)Wvb, Ad * E, 1.0f);

  // W2T[e2][e1] = sum_a Wk[a][e2]*Wq[a][e1] / 32
  gemm128<<<dim3(8, 8), blk, 0, stream>>>(
      WkT, Ad, WqT, Ad, (bf16*)W2T, E, Ad, 0.03125f);

  // Q2 (M x 1024) = Xb . W2T^T
  gemm256<bf16, 0><<<dim3(1024 / 256, M / 256), blk5, 0, stream>>>(
      Xb, E, 0, W2T, E, 0, (bf16*)Q2, 1024, 0, E, 1.0f);

  // all-batch V^T: Vt (Ad x M) = Wvb . Xb^T
  gemm256<bf16, 0><<<dim3(M / 256, Ad / 256), blk5, 0, stream>>>(
      Wvb, E, 0, Xb, E, 0, (bf16*)Vt, M, 0, E, 1.0f);

  // S (256-packed tri, all batches) = Q2 . Xb^T
  gemm256<bf16, 1><<<dim3(136, 1, Bn), blk5, 0, stream>>>(
      Q2, 1024, (size_t)T * 1024,
      Xb, 1024, (size_t)T * 1024,
      (bf16*)SP, 256, SPz, E, 1.0f);

  // in-place softmax on packed scores (all batches)
  softmax_causal_packed<<<dim3(T, Bn), blk, 0, stream>>>(SP, T);

  // O = P.V (256-packed P; causal K-limit)
  gemm256<float, 2><<<dim3(Ad / 256, T / 256, Bn), blk5, 0, stream>>>(
      SP, 256, SPz,
      Vt, M, (size_t)T,
      Out, Ad, (size_t)T * Ad, T, 1.0f);
}

// Round 18
// 394.167 us; speedup vs baseline: 4.4904x; 4.4904x over previous
//
#include <hip/hip_runtime.h>
#include <hip/hip_bf16.h>

using bf16 = __hip_bfloat16;

typedef __attribute__((ext_vector_type(4))) float f32x4;
typedef __attribute__((ext_vector_type(8))) short short8;

typedef const void __attribute__((address_space(1)))* gas1_t;
typedef void __attribute__((address_space(3)))* las3_t;
#define GLDS(gp, lp) __builtin_amdgcn_global_load_lds((gas1_t)(gp), (las3_t)(lp), 16, 0, 0)

__device__ inline short f2bfbits(float f) {
  union { bf16 h; short s; } u;
  u.h = __float2bfloat16(f);
  return u.s;
}
__device__ inline float bf2f(short u) {
  unsigned x = ((unsigned)(unsigned short)u) << 16;
  float f; __builtin_memcpy(&f, &x, 4); return f;
}

__device__ inline void store_out(float* C, size_t idx, float v) { C[idx] = v; }
__device__ inline void store_out(bf16* C, size_t idx, float v) { C[idx] = __float2bfloat16(v); }

// ---------------------------------------------------------------------------
// 256x256 tile GEMM, BK=32, 512 thr = 8 waves (2M x 4N). 2-BUFFER (64 KB
// LDS -> 2 blocks/CU via LDS limit) with __launch_bounds__(512,2): VGPR
// budget 256 so ~92-VGPR body does NOT spill (r17's (512,4) forced 64 VGPR
// -> acc spill -> 1.4 GB scratch writes). Loop = r15 two-phase body; stage
// of tile kt+1 split across phases (A-half then B-half); plain drain at tile
// end, covered by cross-block TLP (m114). Chunk-XOR swizzle kept (r15<r16).
// MODE 0: plain, identity raster.
// MODE 1: causal S -> tri grid, C to 256-packed tri bf16.
// MODE 2: PV -> A is 256-packed P, K limited to (by+1)*256.
// ---------------------------------------------------------------------------
template<typename TOUT, int MODE>
__global__ __launch_bounds__(512, 2) void gemm256(
    const short* __restrict__ A, int lda, size_t sAz,
    const short* __restrict__ B, int ldb, size_t sBz,
    TOUT* __restrict__ C, int ldc, size_t sCz,
    int K, float scale)
{
  int bx, by;
  if constexpr (MODE == 1) {
    const int i = blockIdx.x;
    by = (int)((__builtin_sqrtf(8.f * (float)i + 1.f) - 1.f) * 0.5f);
    if (((by * (by + 1)) >> 1) > i) by--;
    else if ((((by + 1) * (by + 2)) >> 1) <= i) by++;
    bx = i - ((by * (by + 1)) >> 1);
  } else {
    bx = blockIdx.x; by = blockIdx.y;
  }
  const int z = blockIdx.z;
  const int tri_by = (by * (by + 1)) >> 1;

  A += (size_t)z * sAz;
  B += (size_t)z * sBz;
  C += (size_t)z * sCz;

  int Klen = K;
  if (MODE == 2) Klen = min(K, (by + 1) * 256);
  const int NT = Klen >> 5;

  __shared__ short As[2][256 * 32];   // 2 x 16 KB
  __shared__ short Bs[2][256 * 32];   // 2 x 16 KB (64 KB total -> 2 blocks/CU)

  const int t = threadIdx.x;
  const int lane = t & 63;
  const int wave = t >> 6;
  const int wm = wave >> 2;
  const int wn = wave & 3;
  const int fr = lane & 15, kh = lane >> 4;
  const int koff = ((kh ^ ((fr >> 1) & 3)) << 3);   // swizzled 8-short chunk

  int srow[2], scol[2];
  #pragma unroll
  for (int j = 0; j < 2; j++) {
    int e = j * 512 + t;
    srow[j] = e >> 2;
    scol[j] = (((e & 3) ^ ((e >> 3) & 3)) << 3);    // pre-swizzled source
  }

  f32x4 acc[8][4];
  #pragma unroll
  for (int i = 0; i < 8; i++)
    #pragma unroll
    for (int j = 0; j < 4; j++) acc[i][j] = (f32x4){0.f, 0.f, 0.f, 0.f};

  auto STAGE_A = [&](int kt) {
    const int buf = kt & 1, k0 = kt * 32;
    #pragma unroll
    for (int j = 0; j < 2; j++) {
      const short* pa;
      if constexpr (MODE == 2)
        pa = A + (size_t)(tri_by + (k0 >> 8)) * 65536 + (size_t)srow[j] * 256 + (k0 & 255) + scol[j];
      else
        pa = A + (size_t)(by * 256 + srow[j]) * lda + k0 + scol[j];
      GLDS(pa, (char*)&As[buf][0] + j * 8192 + wave * 1024);
    }
  };
  auto STAGE_B = [&](int kt) {
    const int buf = kt & 1, k0 = kt * 32;
    #pragma unroll
    for (int j = 0; j < 2; j++) {
      const short* pb = B + (size_t)(bx * 256 + srow[j]) * ldb + k0 + scol[j];
      GLDS(pb, (char*)&Bs[buf][0] + j * 8192 + wave * 1024);
    }
  };

  STAGE_A(0); STAGE_B(0);
  asm volatile("s_waitcnt vmcnt(0)\ns_barrier" ::: "memory");

  const int arow = wm * 128 + fr;
  const int brow = wn * 64 + fr;

  for (int kt = 0; kt < NT; kt++) {
    const short* as = &As[kt & 1][0];
    const short* bs = &Bs[kt & 1][0];
    short8 af[4], bfr[4];

    // ---- phase A: frags (m0-3) x (n0-3); stage A-half of kt+1 ----
    #pragma unroll
    for (int n = 0; n < 4; n++) bfr[n] = *(const short8*)&bs[(brow + n * 16) * 32 + koff];
    #pragma unroll
    for (int m = 0; m < 4; m++) af[m] = *(const short8*)&as[(arow + m * 16) * 32 + koff];
    if (kt + 1 < NT) STAGE_A(kt + 1);
    asm volatile("s_waitcnt lgkmcnt(0)" ::: "memory");
    __builtin_amdgcn_sched_barrier(0);
    __builtin_amdgcn_s_setprio(1);
    #pragma unroll
    for (int m = 0; m < 4; m++)
      #pragma unroll
      for (int n = 0; n < 4; n++)
        acc[m][n] = __builtin_amdgcn_mfma_f32_16x16x32_bf16(af[m], bfr[n], acc[m][n], 0, 0, 0);
    __builtin_amdgcn_s_setprio(0);
    __builtin_amdgcn_sched_barrier(0);

    // ---- phase B: frags (m4-7) x (n0-3); stage B-half of kt+1 ----
    #pragma unroll
    for (int m = 0; m < 4; m++) af[m] = *(const short8*)&as[(arow + (m + 4) * 16) * 32 + koff];
    if (kt + 1 < NT) STAGE_B(kt + 1);
    asm volatile("s_waitcnt lgkmcnt(0)" ::: "memory");
    __builtin_amdgcn_sched_barrier(0);
    __builtin_amdgcn_s_setprio(1);
    #pragma unroll
    for (int m = 0; m < 4; m++)
      #pragma unroll
      for (int n = 0; n < 4; n++)
        acc[m + 4][n] = __builtin_amdgcn_mfma_f32_16x16x32_bf16(af[m], bfr[n], acc[m + 4][n], 0, 0, 0);
    __builtin_amdgcn_s_setprio(0);
    __builtin_amdgcn_sched_barrier(0);

    // tile end: drain (only tile kt+1 in flight); cross-block TLP covers it
    if (kt + 1 < NT)
      asm volatile("s_waitcnt vmcnt(0)\ns_barrier" ::: "memory");
  }

  #pragma unroll
  for (int m = 0; m < 8; m++)
    #pragma unroll
    for (int n = 0; n < 4; n++) {
      int col_l = wn * 64 + n * 16 + fr;
      #pragma unroll
      for (int r = 0; r < 4; r++) {
        int row_l = wm * 128 + m * 16 + kh * 4 + r;
        if constexpr (MODE == 1)
          store_out(C, (size_t)(tri_by + bx) * 65536 + (size_t)row_l * 256 + col_l,
                    acc[m][n][r] * scale);
        else
          store_out(C, (size_t)(by * 256 + row_l) * ldc + bx * 256 + col_l,
                    acc[m][n][r] * scale);
      }
    }
}

// ---------------------------------------------------------------------------
// Small 128x128 GEMM (round-3 proven loop) — only for W2T = Wk^T.Wq (8x8).
// ---------------------------------------------------------------------------
__global__ __launch_bounds__(256) void gemm128(
    const short* __restrict__ A, int lda,
    const short* __restrict__ B, int ldb,
    bf16* __restrict__ C, int ldc, int K, float scale)
{
  const int bx = blockIdx.x, by = blockIdx.y;
  __shared__ short a_lds[128 * 32];
  __shared__ short b_lds[128 * 32];

  const int t = threadIdx.x;
  const int lane = t & 63;
  const int wave = t >> 6;
  const int wm = wave >> 1, wn = wave & 1;
  const int fr = lane & 15, kh = lane >> 4;

  f32x4 acc[4][4];
  #pragma unroll
  for (int i = 0; i < 4; i++)
    #pragma unroll
    for (int j = 0; j < 4; j++) acc[i][j] = (f32x4){0.f, 0.f, 0.f, 0.f};

  for (int k0 = 0; k0 < K; k0 += 32) {
    #pragma unroll
    for (int i = 0; i < 2; i++) {
      int e = i * 256 + t;
      int r_ = e >> 2, c_ = (e & 3) * 8;
      GLDS(A + (size_t)(by * 128 + r_) * lda + k0 + c_, (char*)a_lds + i * 4096 + wave * 1024);
      GLDS(B + (size_t)(bx * 128 + r_) * ldb + k0 + c_, (char*)b_lds + i * 4096 + wave * 1024);
    }
    __syncthreads();

    short8 af[4], bfr[4];
    #pragma unroll
    for (int m = 0; m < 4; m++)
      af[m] = *(const short8*)&a_lds[(wm * 64 + m * 16 + fr) * 32 + kh * 8];
    #pragma unroll
    for (int n = 0; n < 4; n++)
      bfr[n] = *(const short8*)&b_lds[(wn * 64 + n * 16 + fr) * 32 + kh * 8];
    #pragma unroll
    for (int m = 0; m < 4; m++)
      #pragma unroll
      for (int n = 0; n < 4; n++)
        acc[m][n] = __builtin_amdgcn_mfma_f32_16x16x32_bf16(af[m], bfr[n], acc[m][n], 0, 0, 0);
    __syncthreads();
  }

  #pragma unroll
  for (int m = 0; m < 4; m++)
    #pragma unroll
    for (int n = 0; n < 4; n++) {
      int col = bx * 128 + wn * 64 + n * 16 + fr;
      #pragma unroll
      for (int r = 0; r < 4; r++) {
        int row = by * 128 + wm * 64 + m * 16 + kh * 4 + r;
        C[(size_t)row * ldc + col] = __float2bfloat16(acc[m][n][r] * scale);
      }
    }
}

// fp32 -> bf16 elementwise convert with scale
__global__ __launch_bounds__(256) void cvt_bf16(
    const float* __restrict__ in, bf16* __restrict__ out, int n, float scale)
{
  for (int i = (blockIdx.x * 256 + threadIdx.x) * 8; i < n; i += gridDim.x * 2048) {
    f32x4 v0 = *(const f32x4*)&in[i];
    f32x4 v1 = *(const f32x4*)&in[i + 4];
    short8 o = { f2bfbits(v0[0] * scale), f2bfbits(v0[1] * scale),
                 f2bfbits(v0[2] * scale), f2bfbits(v0[3] * scale),
                 f2bfbits(v1[0] * scale), f2bfbits(v1[1] * scale),
                 f2bfbits(v1[2] * scale), f2bfbits(v1[3] * scale) };
    *(short8*)&out[i] = o;
  }
}

// fp32 (N x N) -> bf16 transposed (N x N): out[c][r] = in[r][c]. 64x64 tiles.
__global__ __launch_bounds__(256) void cvt_t_bf16(
    const float* __restrict__ in, bf16* __restrict__ out, int N)
{
  __shared__ float tile[64][65];
  const int bx = blockIdx.x, by = blockIdx.y;
  const int t = threadIdx.x;
  #pragma unroll
  for (int i = 0; i < 16; i++) {
    int e = i * 256 + t;
    int r = e >> 6, c = e & 63;
    tile[r][c] = in[(size_t)(by * 64 + r) * N + bx * 64 + c];
  }
  __syncthreads();
  #pragma unroll
  for (int i = 0; i < 16; i++) {
    int e = i * 256 + t;
    int r = e >> 6, c = e & 63;
    out[(size_t)(bx * 64 + r) * N + by * 64 + c] = __float2bfloat16(tile[c][r]);
  }
}

// In-place softmax on 256-packed block-triangular bf16 scores.
__global__ __launch_bounds__(256) void softmax_causal_packed(short* SP, int T)
{
  __shared__ float rowv[4096];
  __shared__ float red[4];
  const int r = blockIdx.x;
  const int z = blockIdx.y;
  const int rb = r >> 8, rl = r & 255;
  const size_t tri = (size_t)((rb * (rb + 1)) >> 1);
  short* base = SP + (size_t)z * 136 * 65536;
  const int L = r + 1;
  const int kend = (rb + 1) * 256;
  const int t = threadIdx.x;

  float lmax = -3.0e38f;
  for (int i = t * 8; i < kend; i += 2048) {
    short8 s = *(const short8*)(base + (tri + (i >> 8)) * 65536 + (size_t)rl * 256 + (i & 255));
    #pragma unroll
    for (int j = 0; j < 8; j++) {
      float v = bf2f(s[j]);
      rowv[i + j] = v;
      if (i + j < L) lmax = fmaxf(lmax, v);
    }
  }
  #pragma unroll
  for (int o = 32; o > 0; o >>= 1) lmax = fmaxf(lmax, __shfl_down(lmax, o));
  if ((t & 63) == 0) red[t >> 6] = lmax;
  __syncthreads();
  const float m = fmaxf(fmaxf(red[0], red[1]), fmaxf(red[2], red[3]));
  __syncthreads();

  float lsum = 0.f;
  for (int i = t; i < kend; i += 256) {
    float e = (i < L) ? __expf(rowv[i] - m) : 0.f;
    rowv[i] = e;
    lsum += e;
  }
  #pragma unroll
  for (int o = 32; o > 0; o >>= 1) lsum += __shfl_down(lsum, o);
  if ((t & 63) == 0) red[t >> 6] = lsum;
  __syncthreads();
  const float inv = 1.f / (red[0] + red[1] + red[2] + red[3]);

  for (int i = t * 8; i < kend; i += 2048) {
    short8 o;
    #pragma unroll
    for (int j = 0; j < 8; j++) o[j] = f2bfbits(rowv[i + j] * inv);
    *(short8*)(base + (tri + (i >> 8)) * 65536 + (size_t)rl * 256 + (i & 255)) = o;
  }
}

extern "C" void kernel_launch(void* const* d_in, const int* in_sizes, int n_in,
                              void* d_out, int out_size, void* d_ws, size_t ws_size,
                              hipStream_t stream) {
  (void)in_sizes; (void)n_in; (void)out_size; (void)ws_size;
  const float* X  = (const float*)d_in[0];   // (B,T,E)
  const float* Wq = (const float*)d_in[1];   // (A,E)
  const float* Wk = (const float*)d_in[2];
  const float* Wv = (const float*)d_in[3];
  float* Out = (float*)d_out;                // (B,T,A) fp32

  const int Bn = 4, T = 4096, E = 1024, Ad = 1024;
  const int M = Bn * T;  // 16384

  // Algebra: S = X.(Wq^T Wk / 32).X^T  — K-projection eliminated
  char* ws = (char*)d_ws;
  short* Q2  = (short*)ws;                    // [0,32Mi)   M x 1024
  short* Vt  = (short*)(ws + 33554432);       // [32,64Mi)  Ad x M
  short* Xb  = (short*)(ws + 67108864);       // [64,96Mi)  M x E
  short* WqT = (short*)(ws + 100663296);      // E x A
  short* WkT = (short*)(ws + 102760448);
  short* Wvb = (short*)(ws + 104857600);
  short* W2T = (short*)(ws + 106954752);
  short* SP  = (short*)(ws + 109051904);      // 4 x 136 x 256x256 bf16

  dim3 blk(256), blk5(512);
  const size_t SPz = (size_t)136 * 65536;

  // conversions
  cvt_bf16<<<dim3(8192), blk, 0, stream>>>(X, (bf16*)Xb, M * E, 1.0f);
  cvt_t_bf16<<<dim3(16, 16), blk, 0, stream>>>(Wq, (bf16*)WqT, E);
  cvt_t_bf16<<<dim3(16, 16), blk, 0, stream>>>(Wk, (bf16*)WkT, E);
  cvt_bf16<<<dim3(512), blk, 0, stream>>>(Wv, (bf16*)Wvb, Ad * E, 1.0f);

  // W2T[e2][e1] = sum_a Wk[a][e2]*Wq[a][e1] / 32
  gemm128<<<dim3(8, 8), blk, 0, stream>>>(
      WkT, Ad, WqT, Ad, (bf16*)W2T, E, Ad, 0.03125f);

  // Q2 (M x 1024) = Xb . W2T^T
  gemm256<bf16, 0><<<dim3(1024 / 256, M / 256), blk5, 0, stream>>>(
      Xb, E, 0, W2T, E, 0, (bf16*)Q2, 1024, 0, E, 1.0f);

  // all-batch V^T: Vt (Ad x M) = Wvb . Xb^T
  gemm256<bf16, 0><<<dim3(M / 256, Ad / 256), blk5, 0, stream>>>(
      Wvb, E, 0, Xb, E, 0, (bf16*)Vt, M, 0, E, 1.0f);

  // S (256-packed tri, all batches) = Q2 . Xb^T
  gemm256<bf16, 1><<<dim3(136, 1, Bn), blk5, 0, stream>>>(
      Q2, 1024, (size_t)T * 1024,
      Xb, 1024, (size_t)T * 1024,
      (bf16*)SP, 256, SPz, E, 1.0f);

  // in-place softmax on packed scores (all batches)
  softmax_causal_packed<<<dim3(T, Bn), blk, 0, stream>>>(SP, T);

  // O = P.V (256-packed P; causal K-limit)
  gemm256<float, 2><<<dim3(Ad / 256, T / 256, Bn), blk5, 0, stream>>>(
      SP, 256, SPz,
      Vt, M, (size_t)T,
      Out, Ad, (size_t)T * Ad, T, 1.0f);
}

// Round 19
// 384.358 us; speedup vs baseline: 4.6050x; 1.0255x over previous
//
#include <hip/hip_runtime.h>
#include <hip/hip_bf16.h>

using bf16 = __hip_bfloat16;

typedef __attribute__((ext_vector_type(4))) float f32x4;
typedef __attribute__((ext_vector_type(8))) short short8;

typedef const void __attribute__((address_space(1)))* gas1_t;
typedef void __attribute__((address_space(3)))* las3_t;
#define GLDS(gp, lp) __builtin_amdgcn_global_load_lds((gas1_t)(gp), (las3_t)(lp), 16, 0, 0)

__device__ inline short f2bfbits(float f) {
  union { bf16 h; short s; } u;
  u.h = __float2bfloat16(f);
  return u.s;
}
__device__ inline float bf2f(short u) {
  unsigned x = ((unsigned)(unsigned short)u) << 16;
  float f; __builtin_memcpy(&f, &x, 4); return f;
}

__device__ inline void store_out(float* C, size_t idx, float v) { C[idx] = v; }
__device__ inline void store_out(bf16* C, size_t idx, float v) { C[idx] = __float2bfloat16(v); }

// ---------------------------------------------------------------------------
// ROUND-15 gemm256 VERBATIM (best total 384us): 256x256, BK=32, 8 waves,
// 3-ring LDS + counted vmcnt(4), chunk-XOR swizzle. MODE 0: plain;
// MODE 1: causal S -> tri grid, 256-packed tri bf16 out.
// ---------------------------------------------------------------------------
template<typename TOUT, int MODE>
__global__ __launch_bounds__(512, 2) void gemm256(
    const short* __restrict__ A, int lda, size_t sAz,
    const short* __restrict__ B, int ldb, size_t sBz,
    TOUT* __restrict__ C, int ldc, size_t sCz,
    int K, float scale)
{
  int bx, by;
  if constexpr (MODE == 1) {
    const int i = blockIdx.x;
    by = (int)((__builtin_sqrtf(8.f * (float)i + 1.f) - 1.f) * 0.5f);
    if (((by * (by + 1)) >> 1) > i) by--;
    else if ((((by + 1) * (by + 2)) >> 1) <= i) by++;
    bx = i - ((by * (by + 1)) >> 1);
  } else {
    bx = blockIdx.x; by = blockIdx.y;
  }
  const int z = blockIdx.z;
  const int tri_by = (by * (by + 1)) >> 1;

  A += (size_t)z * sAz;
  B += (size_t)z * sBz;
  C += (size_t)z * sCz;

  const int NT = K >> 5;

  __shared__ short As[3][256 * 32];
  __shared__ short Bs[3][256 * 32];

  const int t = threadIdx.x;
  const int lane = t & 63;
  const int wave = t >> 6;
  const int wm = wave >> 2;
  const int wn = wave & 3;
  const int fr = lane & 15, kh = lane >> 4;
  const int koff = ((kh ^ ((fr >> 1) & 3)) << 3);

  int srow[2], scol[2];
  #pragma unroll
  for (int j = 0; j < 2; j++) {
    int e = j * 512 + t;
    srow[j] = e >> 2;
    scol[j] = (((e & 3) ^ ((e >> 3) & 3)) << 3);
  }

  f32x4 acc[8][4];
  #pragma unroll
  for (int i = 0; i < 8; i++)
    #pragma unroll
    for (int j = 0; j < 4; j++) acc[i][j] = (f32x4){0.f, 0.f, 0.f, 0.f};

  auto STAGE_A = [&](int kt) {
    const int buf = kt % 3, k0 = kt * 32;
    #pragma unroll
    for (int j = 0; j < 2; j++) {
      const short* pa = A + (size_t)(by * 256 + srow[j]) * lda + k0 + scol[j];
      GLDS(pa, (char*)&As[buf][0] + j * 8192 + wave * 1024);
    }
  };
  auto STAGE_B = [&](int kt) {
    const int buf = kt % 3, k0 = kt * 32;
    #pragma unroll
    for (int j = 0; j < 2; j++) {
      const short* pb = B + (size_t)(bx * 256 + srow[j]) * ldb + k0 + scol[j];
      GLDS(pb, (char*)&Bs[buf][0] + j * 8192 + wave * 1024);
    }
  };

  STAGE_A(0); STAGE_B(0);
  STAGE_A(1); STAGE_B(1);
  asm volatile("s_waitcnt vmcnt(4)\ns_barrier" ::: "memory");

  const int arow = wm * 128 + fr;
  const int brow = wn * 64 + fr;

  for (int kt = 0; kt < NT; kt++) {
    const short* as = &As[kt % 3][0];
    const short* bs = &Bs[kt % 3][0];
    short8 af[4], bfr[4];

    #pragma unroll
    for (int n = 0; n < 4; n++) bfr[n] = *(const short8*)&bs[(brow + n * 16) * 32 + koff];
    #pragma unroll
    for (int m = 0; m < 4; m++) af[m] = *(const short8*)&as[(arow + m * 16) * 32 + koff];
    if (kt + 2 < NT) STAGE_A(kt + 2);
    __builtin_amdgcn_s_barrier();
    asm volatile("s_waitcnt lgkmcnt(0)" ::: "memory");
    __builtin_amdgcn_sched_barrier(0);
    __builtin_amdgcn_s_setprio(1);
    #pragma unroll
    for (int m = 0; m < 4; m++)
      #pragma unroll
      for (int n = 0; n < 4; n++)
        acc[m][n] = __builtin_amdgcn_mfma_f32_16x16x32_bf16(af[m], bfr[n], acc[m][n], 0, 0, 0);
    __builtin_amdgcn_s_setprio(0);
    __builtin_amdgcn_sched_barrier(0);

    #pragma unroll
    for (int m = 0; m < 4; m++) af[m] = *(const short8*)&as[(arow + (m + 4) * 16) * 32 + koff];
    if (kt + 2 < NT) STAGE_B(kt + 2);
    __builtin_amdgcn_s_barrier();
    asm volatile("s_waitcnt lgkmcnt(0)" ::: "memory");
    __builtin_amdgcn_sched_barrier(0);
    __builtin_amdgcn_s_setprio(1);
    #pragma unroll
    for (int m = 0; m < 4; m++)
      #pragma unroll
      for (int n = 0; n < 4; n++)
        acc[m + 4][n] = __builtin_amdgcn_mfma_f32_16x16x32_bf16(af[m], bfr[n], acc[m + 4][n], 0, 0, 0);
    __builtin_amdgcn_s_setprio(0);
    __builtin_amdgcn_sched_barrier(0);

    if (kt + 2 < NT)      asm volatile("s_waitcnt vmcnt(4)\ns_barrier" ::: "memory");
    else if (kt + 1 < NT) asm volatile("s_waitcnt vmcnt(0)\ns_barrier" ::: "memory");
  }

  #pragma unroll
  for (int m = 0; m < 8; m++)
    #pragma unroll
    for (int n = 0; n < 4; n++) {
      int col_l = wn * 64 + n * 16 + fr;
      #pragma unroll
      for (int r = 0; r < 4; r++) {
        int row_l = wm * 128 + m * 16 + kh * 4 + r;
        if constexpr (MODE == 1)
          store_out(C, (size_t)(tri_by + bx) * 65536 + (size_t)row_l * 256 + col_l,
                    acc[m][n][r] * scale);
        else
          store_out(C, (size_t)(by * 256 + row_l) * ldc + bx * 256 + col_l,
                    acc[m][n][r] * scale);
      }
    }
}

// ---------------------------------------------------------------------------
// PV balanced: BM=256 x BN=128, 256 thr = 4 waves (2M x 2N), per-wave 128x64.
// 48 KB 2-buffer LDS -> 3 blocks/CU; grid 512 with complementary pairing:
// w and w+256 (same CU slot under round-robin) get by = g and 15-g, so
// per-CU causal K-work is constant 17*256 rows (fixes the by=15 makespan
// that pinned PV at 127us with 1 block/CU). A = 256-packed tri P.
// ---------------------------------------------------------------------------
__global__ __launch_bounds__(256, 2) void gemm_pv(
    const short* __restrict__ SP, const short* __restrict__ Vt,
    float* __restrict__ Out)
{
  const int w = blockIdx.x;
  const int k = w >> 8, c = w & 255;
  const int bx = c & 7;                 // 8 x 128-col slices of Ad
  const int g = (c >> 3) & 7;
  const int z = c >> 6;                 // 4 batches
  const int by = k ? 15 - g : g;        // complementary pair
  const int tri_by = (by * (by + 1)) >> 1;

  const short* A = SP + (size_t)z * 136 * 65536;
  const int Klen = (by + 1) * 256;
  const int NT = Klen >> 5;

  __shared__ short As[2][256 * 32];     // 2 x 16 KB
  __shared__ short Bs[2][128 * 32];     // 2 x 8 KB   (48 KB total)

  const int t = threadIdx.x;
  const int lane = t & 63;
  const int wave = t >> 6;              // 0..3
  const int wm = wave >> 1;             // 0..1 (128-row half)
  const int wn = wave & 1;              // 0..1 (64-col slice)
  const int fr = lane & 15, kh = lane >> 4;
  const int koff = ((kh ^ ((fr >> 1) & 3)) << 3);

  f32x4 acc[8][4];
  #pragma unroll
  for (int i = 0; i < 8; i++)
    #pragma unroll
    for (int j = 0; j < 4; j++) acc[i][j] = (f32x4){0.f, 0.f, 0.f, 0.f};

  auto STAGE_A = [&](int kt) {
    const int buf = kt & 1, k0 = kt * 32;
    #pragma unroll
    for (int j = 0; j < 4; j++) {
      int e = j * 256 + t;
      int row = e >> 2;
      int sc = (((e & 3) ^ ((row >> 1) & 3)) << 3);
      const short* pa = A + (size_t)(tri_by + (k0 >> 8)) * 65536
                          + (size_t)row * 256 + (k0 & 255) + sc;
      GLDS(pa, (char*)&As[buf][0] + j * 4096 + wave * 1024);
    }
  };
  auto STAGE_B = [&](int kt) {
    const int buf = kt & 1, k0 = kt * 32;
    #pragma unroll
    for (int j = 0; j < 2; j++) {
      int e = j * 256 + t;
      int row = e >> 2;
      int sc = (((e & 3) ^ ((row >> 1) & 3)) << 3);
      const short* pb = Vt + (size_t)(bx * 128 + row) * 16384 + z * 4096 + k0 + sc;
      GLDS(pb, (char*)&Bs[buf][0] + j * 4096 + wave * 1024);
    }
  };

  STAGE_A(0); STAGE_B(0);
  asm volatile("s_waitcnt vmcnt(0)\ns_barrier" ::: "memory");

  const int arow = wm * 128 + fr;
  const int brow = wn * 64 + fr;

  for (int kt = 0; kt < NT; kt++) {
    const short* as = &As[kt & 1][0];
    const short* bs = &Bs[kt & 1][0];
    short8 af[4], bfr[4];

    // phase A: frags (m0-3); stage A-half of kt+1
    #pragma unroll
    for (int n = 0; n < 4; n++) bfr[n] = *(const short8*)&bs[(brow + n * 16) * 32 + koff];
    #pragma unroll
    for (int m = 0; m < 4; m++) af[m] = *(const short8*)&as[(arow + m * 16) * 32 + koff];
    if (kt + 1 < NT) STAGE_A(kt + 1);
    asm volatile("s_waitcnt lgkmcnt(0)" ::: "memory");
    __builtin_amdgcn_sched_barrier(0);
    __builtin_amdgcn_s_setprio(1);
    #pragma unroll
    for (int m = 0; m < 4; m++)
      #pragma unroll
      for (int n = 0; n < 4; n++)
        acc[m][n] = __builtin_amdgcn_mfma_f32_16x16x32_bf16(af[m], bfr[n], acc[m][n], 0, 0, 0);
    __builtin_amdgcn_s_setprio(0);
    __builtin_amdgcn_sched_barrier(0);

    // phase B: frags (m4-7); stage B-half of kt+1
    #pragma unroll
    for (int m = 0; m < 4; m++) af[m] = *(const short8*)&as[(arow + (m + 4) * 16) * 32 + koff];
    if (kt + 1 < NT) STAGE_B(kt + 1);
    asm volatile("s_waitcnt lgkmcnt(0)" ::: "memory");
    __builtin_amdgcn_sched_barrier(0);
    __builtin_amdgcn_s_setprio(1);
    #pragma unroll
    for (int m = 0; m < 4; m++)
      #pragma unroll
      for (int n = 0; n < 4; n++)
        acc[m + 4][n] = __builtin_amdgcn_mfma_f32_16x16x32_bf16(af[m], bfr[n], acc[m + 4][n], 0, 0, 0);
    __builtin_amdgcn_s_setprio(0);
    __builtin_amdgcn_sched_barrier(0);

    if (kt + 1 < NT)
      asm volatile("s_waitcnt vmcnt(0)\ns_barrier" ::: "memory");
  }

  float* Cz = Out + (size_t)z * 4096 * 1024;
  #pragma unroll
  for (int m = 0; m < 8; m++)
    #pragma unroll
    for (int n = 0; n < 4; n++) {
      int col = bx * 128 + wn * 64 + n * 16 + fr;
      #pragma unroll
      for (int r = 0; r < 4; r++) {
        int row_l = wm * 128 + m * 16 + kh * 4 + r;
        Cz[(size_t)(by * 256 + row_l) * 1024 + col] = acc[m][n][r];
      }
    }
}

// ---------------------------------------------------------------------------
// Small 128x128 GEMM (round-3 proven loop) — only for W2T = Wk^T.Wq (8x8).
// ---------------------------------------------------------------------------
__global__ __launch_bounds__(256) void gemm128(
    const short* __restrict__ A, int lda,
    const short* __restrict__ B, int ldb,
    bf16* __restrict__ C, int ldc, int K, float scale)
{
  const int bx = blockIdx.x, by = blockIdx.y;
  __shared__ short a_lds[128 * 32];
  __shared__ short b_lds[128 * 32];

  const int t = threadIdx.x;
  const int lane = t & 63;
  const int wave = t >> 6;
  const int wm = wave >> 1, wn = wave & 1;
  const int fr = lane & 15, kh = lane >> 4;

  f32x4 acc[4][4];
  #pragma unroll
  for (int i = 0; i < 4; i++)
    #pragma unroll
    for (int j = 0; j < 4; j++) acc[i][j] = (f32x4){0.f, 0.f, 0.f, 0.f};

  for (int k0 = 0; k0 < K; k0 += 32) {
    #pragma unroll
    for (int i = 0; i < 2; i++) {
      int e = i * 256 + t;
      int r_ = e >> 2, c_ = (e & 3) * 8;
      GLDS(A + (size_t)(by * 128 + r_) * lda + k0 + c_, (char*)a_lds + i * 4096 + wave * 1024);
      GLDS(B + (size_t)(bx * 128 + r_) * ldb + k0 + c_, (char*)b_lds + i * 4096 + wave * 1024);
    }
    __syncthreads();

    short8 af[4], bfr[4];
    #pragma unroll
    for (int m = 0; m < 4; m++)
      af[m] = *(const short8*)&a_lds[(wm * 64 + m * 16 + fr) * 32 + kh * 8];
    #pragma unroll
    for (int n = 0; n < 4; n++)
      bfr[n] = *(const short8*)&b_lds[(wn * 64 + n * 16 + fr) * 32 + kh * 8];
    #pragma unroll
    for (int m = 0; m < 4; m++)
      #pragma unroll
      for (int n = 0; n < 4; n++)
        acc[m][n] = __builtin_amdgcn_mfma_f32_16x16x32_bf16(af[m], bfr[n], acc[m][n], 0, 0, 0);
    __syncthreads();
  }

  #pragma unroll
  for (int m = 0; m < 4; m++)
    #pragma unroll
    for (int n = 0; n < 4; n++) {
      int col = bx * 128 + wn * 64 + n * 16 + fr;
      #pragma unroll
      for (int r = 0; r < 4; r++) {
        int row = by * 128 + wm * 64 + m * 16 + kh * 4 + r;
        C[(size_t)row * ldc + col] = __float2bfloat16(acc[m][n][r] * scale);
      }
    }
}

// fp32 -> bf16 elementwise convert with scale
__global__ __launch_bounds__(256) void cvt_bf16(
    const float* __restrict__ in, bf16* __restrict__ out, int n, float scale)
{
  for (int i = (blockIdx.x * 256 + threadIdx.x) * 8; i < n; i += gridDim.x * 2048) {
    f32x4 v0 = *(const f32x4*)&in[i];
    f32x4 v1 = *(const f32x4*)&in[i + 4];
    short8 o = { f2bfbits(v0[0] * scale), f2bfbits(v0[1] * scale),
                 f2bfbits(v0[2] * scale), f2bfbits(v0[3] * scale),
                 f2bfbits(v1[0] * scale), f2bfbits(v1[1] * scale),
                 f2bfbits(v1[2] * scale), f2bfbits(v1[3] * scale) };
    *(short8*)&out[i] = o;
  }
}

// fp32 (N x N) -> bf16 transposed (N x N): out[c][r] = in[r][c]. 64x64 tiles.
__global__ __launch_bounds__(256) void cvt_t_bf16(
    const float* __restrict__ in, bf16* __restrict__ out, int N)
{
  __shared__ float tile[64][65];
  const int bx = blockIdx.x, by = blockIdx.y;
  const int t = threadIdx.x;
  #pragma unroll
  for (int i = 0; i < 16; i++) {
    int e = i * 256 + t;
    int r = e >> 6, c = e & 63;
    tile[r][c] = in[(size_t)(by * 64 + r) * N + bx * 64 + c];
  }
  __syncthreads();
  #pragma unroll
  for (int i = 0; i < 16; i++) {
    int e = i * 256 + t;
    int r = e >> 6, c = e & 63;
    out[(size_t)(bx * 64 + r) * N + by * 64 + c] = __float2bfloat16(tile[c][r]);
  }
}

// In-place softmax on 256-packed block-triangular bf16 scores.
__global__ __launch_bounds__(256) void softmax_causal_packed(short* SP, int T)
{
  __shared__ float rowv[4096];
  __shared__ float red[4];
  const int r = blockIdx.x;
  const int z = blockIdx.y;
  const int rb = r >> 8, rl = r & 255;
  const size_t tri = (size_t)((rb * (rb + 1)) >> 1);
  short* base = SP + (size_t)z * 136 * 65536;
  const int L = r + 1;
  const int kend = (rb + 1) * 256;
  const int t = threadIdx.x;

  float lmax = -3.0e38f;
  for (int i = t * 8; i < kend; i += 2048) {
    short8 s = *(const short8*)(base + (tri + (i >> 8)) * 65536 + (size_t)rl * 256 + (i & 255));
    #pragma unroll
    for (int j = 0; j < 8; j++) {
      float v = bf2f(s[j]);
      rowv[i + j] = v;
      if (i + j < L) lmax = fmaxf(lmax, v);
    }
  }
  #pragma unroll
  for (int o = 32; o > 0; o >>= 1) lmax = fmaxf(lmax, __shfl_down(lmax, o));
  if ((t & 63) == 0) red[t >> 6] = lmax;
  __syncthreads();
  const float m = fmaxf(fmaxf(red[0], red[1]), fmaxf(red[2], red[3]));
  __syncthreads();

  float lsum = 0.f;
  for (int i = t; i < kend; i += 256) {
    float e = (i < L) ? __expf(rowv[i] - m) : 0.f;
    rowv[i] = e;
    lsum += e;
  }
  #pragma unroll
  for (int o = 32; o > 0; o >>= 1) lsum += __shfl_down(lsum, o);
  if ((t & 63) == 0) red[t >> 6] = lsum;
  __syncthreads();
  const float inv = 1.f / (red[0] + red[1] + red[2] + red[3]);

  for (int i = t * 8; i < kend; i += 2048) {
    short8 o;
    #pragma unroll
    for (int j = 0; j < 8; j++) o[j] = f2bfbits(rowv[i + j] * inv);
    *(short8*)(base + (tri + (i >> 8)) * 65536 + (size_t)rl * 256 + (i & 255)) = o;
  }
}

extern "C" void kernel_launch(void* const* d_in, const int* in_sizes, int n_in,
                              void* d_out, int out_size, void* d_ws, size_t ws_size,
                              hipStream_t stream) {
  (void)in_sizes; (void)n_in; (void)out_size; (void)ws_size;
  const float* X  = (const float*)d_in[0];   // (B,T,E)
  const float* Wq = (const float*)d_in[1];   // (A,E)
  const float* Wk = (const float*)d_in[2];
  const float* Wv = (const float*)d_in[3];
  float* Out = (float*)d_out;                // (B,T,A) fp32

  const int Bn = 4, T = 4096, E = 1024, Ad = 1024;
  const int M = Bn * T;  // 16384

  // Algebra: S = X.(Wq^T Wk / 32).X^T  — K-projection eliminated
  char* ws = (char*)d_ws;
  short* Q2  = (short*)ws;                    // [0,32Mi)   M x 1024
  short* Vt  = (short*)(ws + 33554432);       // [32,64Mi)  Ad x M
  short* Xb  = (short*)(ws + 67108864);       // [64,96Mi)  M x E
  short* WqT = (short*)(ws + 100663296);      // E x A
  short* WkT = (short*)(ws + 102760448);
  short* Wvb = (short*)(ws + 104857600);
  short* W2T = (short*)(ws + 106954752);
  short* SP  = (short*)(ws + 109051904);      // 4 x 136 x 256x256 bf16

  dim3 blk(256), blk5(512);
  const size_t SPz = (size_t)136 * 65536;

  // conversions
  cvt_bf16<<<dim3(8192), blk, 0, stream>>>(X, (bf16*)Xb, M * E, 1.0f);
  cvt_t_bf16<<<dim3(16, 16), blk, 0, stream>>>(Wq, (bf16*)WqT, E);
  cvt_t_bf16<<<dim3(16, 16), blk, 0, stream>>>(Wk, (bf16*)WkT, E);
  cvt_bf16<<<dim3(512), blk, 0, stream>>>(Wv, (bf16*)Wvb, Ad * E, 1.0f);

  // W2T[e2][e1] = sum_a Wk[a][e2]*Wq[a][e1] / 32
  gemm128<<<dim3(8, 8), blk, 0, stream>>>(
      WkT, Ad, WqT, Ad, (bf16*)W2T, E, Ad, 0.03125f);

  // Q2 (M x 1024) = Xb . W2T^T
  gemm256<bf16, 0><<<dim3(1024 / 256, M / 256), blk5, 0, stream>>>(
      Xb, E, 0, W2T, E, 0, (bf16*)Q2, 1024, 0, E, 1.0f);

  // all-batch V^T: Vt (Ad x M) = Wvb . Xb^T
  gemm256<bf16, 0><<<dim3(M / 256, Ad / 256), blk5, 0, stream>>>(
      Wvb, E, 0, Xb, E, 0, (bf16*)Vt, M, 0, E, 1.0f);

  // S (256-packed tri, all batches) = Q2 . Xb^T
  gemm256<bf16, 1><<<dim3(136, 1, Bn), blk5, 0, stream>>>(
      Q2, 1024, (size_t)T * 1024,
      Xb, 1024, (size_t)T * 1024,
      (bf16*)SP, 256, SPz, E, 1.0f);

  // in-place softmax on packed scores (all batches)
  softmax_causal_packed<<<dim3(T, Bn), blk, 0, stream>>>(SP, T);

  // O = P.V — balanced: 512 blocks, complementary by-pairing, 3 blocks/CU
  gemm_pv<<<dim3(512), blk, 0, stream>>>(SP, Vt, Out);
}